// Round 2
// baseline (1668.172 us; speedup 1.0000x reference)
//
#include <hip/hip_runtime.h>
#include <math.h>

#define N_NODES 100000
#define N_EDGES 3200000
#define N_GRAPHS 64
#define IN_DIM 128
#define HID 64
#define BN_EPS 1e-5f

#define BSHIFT 6
#define BSIZE 64
#define NBUCK ((N_NODES + BSIZE - 1) / BSIZE)  // 1563
#define AGG_BLOCKS 2048

// ---------------- bucketed CSR build ----------------
// bucket b = dst >> 6. Pass A: histogram. Pass B: partition (sequential-per-
// bucket writes -> full line utilization, vs 197 MB HBM write for the naive
// random scatter). Pass C: per-bucket place into an ~8 KB cache-resident
// window; also emits deg/rowptr/dinv (kills the global count+scan kernels).

__global__ __launch_bounds__(256) void bhist_k(const int* __restrict__ ei,
                                               int* __restrict__ bcnt) {
  __shared__ int h[NBUCK];
  for (int i = threadIdx.x; i < NBUCK; i += 256) h[i] = 0;
  __syncthreads();
  int stride = gridDim.x * 256;
  for (int e = blockIdx.x * 256 + threadIdx.x; e < N_EDGES; e += stride)
    atomicAdd(&h[ei[N_EDGES + e] >> BSHIFT], 1);
  __syncthreads();
  for (int i = threadIdx.x; i < NBUCK; i += 256) {
    int v = h[i];
    if (v) atomicAdd(&bcnt[i], v);
  }
}

__global__ __launch_bounds__(1024) void bscan_k(const int* __restrict__ bcnt,
                                                int* __restrict__ boff,
                                                int* __restrict__ bcur) {
  __shared__ int sa[2048], sb[2048];
  int t = threadIdx.x;
  for (int i = t; i < 2048; i += 1024) sa[i] = (i < NBUCK) ? bcnt[i] : 0;
  __syncthreads();
  int* src = sa; int* dst = sb;
  for (int o = 1; o < 2048; o <<= 1) {
    for (int i = t; i < 2048; i += 1024)
      dst[i] = src[i] + ((i >= o) ? src[i - o] : 0);
    __syncthreads();
    int* tmp = src; src = dst; dst = tmp;
  }
  for (int i = t; i < 2048; i += 1024) {
    if (i <= NBUCK) {
      int v = (i == 0) ? 0 : src[i - 1];  // exclusive
      boff[i] = v;
      if (i < NBUCK) bcur[i] = v;
    }
  }
}

__global__ __launch_bounds__(256) void part_k(const int* __restrict__ ei,
                                              int* __restrict__ bcur,
                                              unsigned* __restrict__ tmp) {
  int stride = gridDim.x * 256;
  for (int e = blockIdx.x * 256 + threadIdx.x; e < N_EDGES; e += stride) {
    int src = ei[e];
    int dst = ei[N_EDGES + e];
    int b = dst >> BSHIFT;
    int p = atomicAdd(&bcur[b], 1);
    tmp[p] = ((unsigned)(dst & (BSIZE - 1)) << 17) | (unsigned)src;  // src<2^17
  }
}

__global__ __launch_bounds__(256) void place_k(
    const unsigned* __restrict__ tmp, const int* __restrict__ boff,
    int* __restrict__ csr, int* __restrict__ rowptr, int* __restrict__ deg,
    float* __restrict__ dinv) {
  int b = blockIdx.x;
  int base = boff[b], end = boff[b + 1];
  int t = threadIdx.x;
  __shared__ int cnt[BSIZE];
  __shared__ int cur[BSIZE];
  if (t < BSIZE) cnt[t] = 0;
  __syncthreads();
  for (int i = base + t; i < end; i += 256)
    atomicAdd(&cnt[tmp[i] >> 17], 1);
  __syncthreads();
  if (t < 64) {  // wave 0: exclusive scan of 64 degrees
    int v = cnt[t];
    int inc = v;
    for (int o = 1; o < 64; o <<= 1) {
      int u = __shfl_up(inc, o);
      if (t >= o) inc += u;
    }
    int excl = inc - v;
    cur[t] = excl;
    int n = b * BSIZE + t;
    if (n < N_NODES) {
      rowptr[n] = base + excl;
      deg[n] = v;
      dinv[n] = rsqrtf((float)(v + 1));  // +1 self loop
    }
  }
  __syncthreads();
  for (int i = base + t; i < end; i += 256) {
    unsigned e = tmp[i];
    int p = atomicAdd(&cur[e >> 17], 1);
    csr[base + p] = (int)(e & 0x1FFFFu);
  }
}

// ---------------- GEMM: out[n][c] = sum_k in[n][k]*W[k][c], optional BN+ReLU on input ----------------

template <int K, bool APPLY, bool RELU>
__global__ __launch_bounds__(256) void gemm_k(
    const float* __restrict__ X, const float* __restrict__ W,
    const float* __restrict__ scale, const float* __restrict__ shift,
    float* __restrict__ out, int nrows) {
  constexpr int WROW = K + 4;
  __shared__ float wt[64 * WROW];   // wt[c][k]  (W transposed)
  __shared__ float xs[64 * 68];     // xs[r][k]
  const int tid = threadIdx.x;
  const int tc = tid & 15;
  const int tr = tid >> 4;

  for (int idx = tid; idx < K * 64; idx += 256) {
    int k = idx >> 6, c = idx & 63;
    wt[c * WROW + k] = W[idx];
  }

  const int rowbase = blockIdx.x * 64;
  float acc[4][4] = {};

  for (int kc = 0; kc < K; kc += 64) {
    __syncthreads();
    {
      const int kq = tid & 15;
      const int rr = tid >> 4;
#pragma unroll
      for (int p = 0; p < 4; ++p) {
        int r = rr + p * 16;
        int grow = rowbase + r;
        float4 v = make_float4(0.f, 0.f, 0.f, 0.f);
        if (grow < nrows) v = *(const float4*)(X + (size_t)grow * K + kc + kq * 4);
        if (APPLY) {
          int kg = kc + kq * 4;
          float4 sc = *(const float4*)(scale + kg);
          float4 sh = *(const float4*)(shift + kg);
          v.x = v.x * sc.x + sh.x;
          v.y = v.y * sc.y + sh.y;
          v.z = v.z * sc.z + sh.z;
          v.w = v.w * sc.w + sh.w;
          if (RELU) {
            v.x = fmaxf(v.x, 0.f); v.y = fmaxf(v.y, 0.f);
            v.z = fmaxf(v.z, 0.f); v.w = fmaxf(v.w, 0.f);
          }
        }
        *(float4*)(xs + r * 68 + kq * 4) = v;
      }
    }
    __syncthreads();
#pragma unroll 4
    for (int k0 = 0; k0 < 64; k0 += 4) {
      float4 xv[4], wv[4];
#pragma unroll
      for (int i = 0; i < 4; ++i)
        xv[i] = *(const float4*)(xs + (tr * 4 + i) * 68 + k0);
#pragma unroll
      for (int j = 0; j < 4; ++j)
        wv[j] = *(const float4*)(wt + (tc + 16 * j) * WROW + kc + k0);
#pragma unroll
      for (int i = 0; i < 4; ++i)
#pragma unroll
        for (int j = 0; j < 4; ++j)
          acc[i][j] += xv[i].x * wv[j].x + xv[i].y * wv[j].y +
                       xv[i].z * wv[j].z + xv[i].w * wv[j].w;
    }
  }

#pragma unroll
  for (int i = 0; i < 4; ++i) {
    int grow = rowbase + tr * 4 + i;
    if (grow < nrows) {
#pragma unroll
      for (int j = 0; j < 4; ++j)
        out[(size_t)grow * 64 + tc + 16 * j] = acc[i][j];
    }
  }
}

// ---------------- edge aggregation + fused BN partial stats ----------------
// one wave per node (lane = feature), grid-stride; per-lane s/s2 partials.

__global__ __launch_bounds__(256) void agg_k(
    const float* __restrict__ h, const float* __restrict__ dinv,
    const int* __restrict__ rowptr, const int* __restrict__ deg,
    const int* __restrict__ csr, const float* __restrict__ bias,
    float* __restrict__ out, float* __restrict__ part) {
  int w = threadIdx.x >> 6;
  int lane = threadIdx.x & 63;
  float bval = bias[lane];
  float s = 0.f, s2 = 0.f;
  for (int n = blockIdx.x * 4 + w; n < N_NODES; n += AGG_BLOCKS * 4) {
    float dn = dinv[n];
    float acc = h[(size_t)n * 64 + lane] * dn * dn;  // self loop
    int start = rowptr[n];
    int cnt = deg[n];
    for (int j0 = 0; j0 < cnt; j0 += 64) {
      int rem = cnt - j0;
      int m = rem < 64 ? rem : 64;
      int mysrc = 0; float myw = 0.f;
      if (lane < m) { mysrc = csr[start + j0 + lane]; myw = dinv[mysrc]; }
      for (int jj = 0; jj < m; ++jj) {
        int src = __shfl(mysrc, jj);
        float wgt = __shfl(myw, jj) * dn;
        acc += h[(size_t)src * 64 + lane] * wgt;
      }
    }
    float val = acc + bval;
    out[(size_t)n * 64 + lane] = val;
    s += val; s2 += val * val;
  }
  __shared__ float ls[4][64], ls2[4][64];
  ls[w][lane] = s; ls2[w][lane] = s2;
  __syncthreads();
  if (w == 0) {
    s = ls[0][lane] + ls[1][lane] + ls[2][lane] + ls[3][lane];
    s2 = ls2[0][lane] + ls2[1][lane] + ls2[2][lane] + ls2[3][lane];
    part[blockIdx.x * 128 + lane] = s;
    part[blockIdx.x * 128 + 64 + lane] = s2;
  }
}

__global__ void bnfinal_k(const float* __restrict__ part,
                          const float* __restrict__ gamma, const float* __restrict__ beta,
                          float* __restrict__ scale, float* __restrict__ shift) {
  __shared__ float ls[4][64], ls2[4][64];
  int c = threadIdx.x & 63, q = threadIdx.x >> 6;
  float s = 0.f, s2 = 0.f;
  for (int b = q; b < AGG_BLOCKS; b += 4) {
    s += part[b * 128 + c];
    s2 += part[b * 128 + 64 + c];
  }
  ls[q][c] = s; ls2[q][c] = s2;
  __syncthreads();
  if (q == 0) {
    s = ls[0][c] + ls[1][c] + ls[2][c] + ls[3][c];
    s2 = ls2[0][c] + ls2[1][c] + ls2[2][c] + ls2[3][c];
    float mean = s / (float)N_NODES;
    float var = s2 / (float)N_NODES - mean * mean;
    float sc = gamma[c] * rsqrtf(var + BN_EPS);
    scale[c] = sc;
    shift[c] = beta[c] - mean * sc;
  }
}

// ---------------- pooling (batch is sorted) ----------------

#define POOL_CHUNK 64
__global__ __launch_bounds__(64) void pool_k(
    const float* __restrict__ h, const float* __restrict__ scale,
    const float* __restrict__ shift, const int* __restrict__ batch,
    float* __restrict__ psum, float* __restrict__ pcnt) {
  int lane = threadIdx.x;
  int start = blockIdx.x * POOL_CHUNK;
  if (start >= N_NODES) return;
  int end = min(start + POOL_CHUNK, N_NODES);
  float sc = scale[lane], sh = shift[lane];
  float acc = 0.f, cnt = 0.f;
  int cur = batch[start];
  for (int n = start; n < end; ++n) {
    int g = batch[n];
    if (g != cur) {
      atomicAdd(&psum[cur * 64 + lane], acc);
      if (lane == 0) atomicAdd(&pcnt[cur], cnt);
      acc = 0.f; cnt = 0.f; cur = g;
    }
    acc += h[(size_t)n * 64 + lane] * sc + sh;
    cnt += 1.f;
  }
  atomicAdd(&psum[cur * 64 + lane], acc);
  if (lane == 0) atomicAdd(&pcnt[cur], cnt);
}

// ---------------- centroid classifier ----------------

__global__ void classify_k(const float* __restrict__ psum, const float* __restrict__ pcnt,
                           const float* __restrict__ cg, const float* __restrict__ cm,
                           const float* __restrict__ temp, float* __restrict__ out) {
  int g = blockIdx.x;
  int t = threadIdx.x;
  __shared__ float emb[64];
  __shared__ float dist[208];
  if (t < 64) emb[t] = psum[g * 64 + t] / fmaxf(pcnt[g], 1.0f);
  __syncthreads();
  if (t < 197) {
    const float* C = (t < 5) ? (cg + t * 64) : (cm + (t - 5) * 64);
    float d = 0.f;
#pragma unroll 8
    for (int k = 0; k < 64; ++k) {
      float df = emb[k] - C[k];
      d += df * df;
    }
    dist[t] = d;
  }
  __syncthreads();
  float tv = temp[0];
  if (t == 64) {
    float m = dist[0];
    for (int j = 1; j < 5; ++j) m = fminf(m, dist[j]);
    out[g * 65] = -m / tv;
  }
  if (t < 64) {
    float m = fminf(dist[5 + t * 3], fminf(dist[5 + t * 3 + 1], dist[5 + t * 3 + 2]));
    out[g * 65 + 1 + t] = -m / tv;
  }
}

// ---------------- launch ----------------

extern "C" void kernel_launch(void* const* d_in, const int* in_sizes, int n_in,
                              void* d_out, int out_size, void* d_ws, size_t ws_size,
                              hipStream_t stream) {
  const float* x   = (const float*)d_in[0];
  const int* ei    = (const int*)d_in[1];
  const int* batch = (const int*)d_in[2];
  const float* W1 = (const float*)d_in[3];  const float* b1 = (const float*)d_in[4];
  const float* g1 = (const float*)d_in[5];  const float* be1 = (const float*)d_in[6];
  const float* W2 = (const float*)d_in[7];  const float* b2 = (const float*)d_in[8];
  const float* g2 = (const float*)d_in[9];  const float* be2 = (const float*)d_in[10];
  const float* W3 = (const float*)d_in[11]; const float* b3 = (const float*)d_in[12];
  const float* g3 = (const float*)d_in[13]; const float* be3 = (const float*)d_in[14];
  const float* cg = (const float*)d_in[15];
  const float* cm = (const float*)d_in[16];
  const float* temp = (const float*)d_in[17];
  float* out = (float*)d_out;

  char* ws = (char*)d_ws;
  size_t off = 0;
  auto alloc = [&](size_t bytes) -> void* {
    void* p = ws + off;
    off = (off + bytes + 255) & ~(size_t)255;
    return p;
  };
  int* bcnt      = (int*)alloc((size_t)NBUCK * 4);
  int* boff      = (int*)alloc((size_t)(NBUCK + 1) * 4);
  int* bcur      = (int*)alloc((size_t)NBUCK * 4);
  unsigned* tmp  = (unsigned*)alloc((size_t)N_EDGES * 4);
  int* csr       = (int*)alloc((size_t)N_EDGES * 4);
  int* rowptr    = (int*)alloc((size_t)N_NODES * 4);
  int* deg       = (int*)alloc((size_t)N_NODES * 4);
  float* dinv    = (float*)alloc((size_t)N_NODES * 4);
  float* hA      = (float*)alloc((size_t)N_NODES * 64 * 4);
  float* hB      = (float*)alloc((size_t)N_NODES * 64 * 4);
  float* part    = (float*)alloc((size_t)AGG_BLOCKS * 128 * 4);
  float* scale   = (float*)alloc(64 * 4);
  float* shift   = (float*)alloc(64 * 4);
  float* psum    = (float*)alloc(64 * 64 * 4);
  float* pcnt    = (float*)alloc(64 * 4);

  hipMemsetAsync(bcnt, 0, (size_t)NBUCK * 4, stream);
  hipMemsetAsync(psum, 0, 64 * 64 * 4, stream);
  hipMemsetAsync(pcnt, 0, 64 * 4, stream);

  const int NB_GEMM = (N_NODES + 63) / 64;   // 1563
  const int NB_POOL = (N_NODES + POOL_CHUNK - 1) / POOL_CHUNK;

  // CSR build via bucketed counting sort
  bhist_k<<<512, 256, 0, stream>>>(ei, bcnt);
  bscan_k<<<1, 1024, 0, stream>>>(bcnt, boff, bcur);
  part_k<<<4096, 256, 0, stream>>>(ei, bcur, tmp);
  place_k<<<NBUCK, 256, 0, stream>>>(tmp, boff, csr, rowptr, deg, dinv);

  // layer 1
  gemm_k<IN_DIM, false, false><<<NB_GEMM, 256, 0, stream>>>(x, W1, nullptr, nullptr, hA, N_NODES);
  agg_k<<<AGG_BLOCKS, 256, 0, stream>>>(hA, dinv, rowptr, deg, csr, b1, hB, part);
  bnfinal_k<<<1, 256, 0, stream>>>(part, g1, be1, scale, shift);

  // layer 2 (BN1+ReLU applied on GEMM input load)
  gemm_k<HID, true, true><<<NB_GEMM, 256, 0, stream>>>(hB, W2, scale, shift, hA, N_NODES);
  agg_k<<<AGG_BLOCKS, 256, 0, stream>>>(hA, dinv, rowptr, deg, csr, b2, hB, part);
  bnfinal_k<<<1, 256, 0, stream>>>(part, g2, be2, scale, shift);

  // layer 3
  gemm_k<HID, true, true><<<NB_GEMM, 256, 0, stream>>>(hB, W3, scale, shift, hA, N_NODES);
  agg_k<<<AGG_BLOCKS, 256, 0, stream>>>(hA, dinv, rowptr, deg, csr, b3, hB, part);
  bnfinal_k<<<1, 256, 0, stream>>>(part, g3, be3, scale, shift);

  // pool (BN3 applied here) + classify
  pool_k<<<NB_POOL, 64, 0, stream>>>(hB, scale, shift, batch, psum, pcnt);
  classify_k<<<N_GRAPHS, 256, 0, stream>>>(psum, pcnt, cg, cm, temp, out);
}

// Round 3
// 1300.300 us; speedup vs baseline: 1.2829x; 1.2829x over previous
//
#include <hip/hip_runtime.h>
#include <math.h>

#define N_NODES 100000
#define N_EDGES 3200000
#define N_GRAPHS 64
#define IN_DIM 128
#define HID 64
#define BN_EPS 1e-5f

#define SCAN_CHUNK 1024
#define NBLK_SCAN ((N_NODES + SCAN_CHUNK - 1) / SCAN_CHUNK)  // 98
#define AGG_BLOCKS 2048

// ---------------- degree / CSR build (round-1 scheme: low-contention atomics) ----------------

__global__ void count_deg_k(const int* __restrict__ ei, int* __restrict__ deg) {
  int e = blockIdx.x * blockDim.x + threadIdx.x;
  if (e < N_EDGES) atomicAdd(&deg[ei[N_EDGES + e]], 1);
}

__global__ void dinv_k(const int* __restrict__ deg, float* __restrict__ dinv) {
  int n = blockIdx.x * blockDim.x + threadIdx.x;
  if (n < N_NODES) dinv[n] = rsqrtf((float)(deg[n] + 1));  // +1 self loop
}

__global__ __launch_bounds__(256) void scan_a_k(const int* __restrict__ deg,
                                                int* __restrict__ bsum) {
  int t = threadIdx.x;
  int base = blockIdx.x * SCAN_CHUNK;
  int s = 0;
  for (int p = 0; p < 4; ++p) {
    int i = base + t + p * 256;
    if (i < N_NODES) s += deg[i];
  }
  __shared__ int red[256];
  red[t] = s; __syncthreads();
  for (int o = 128; o > 0; o >>= 1) {
    if (t < o) red[t] += red[t + o];
    __syncthreads();
  }
  if (t == 0) bsum[blockIdx.x] = red[0];
}

__global__ void scan_b_k(int* bsum) {
  __shared__ int sa[128], sb[128];
  int t = threadIdx.x;
  int* src = sa; int* dst = sb;
  sa[t] = (t < NBLK_SCAN) ? bsum[t] : 0;
  __syncthreads();
  for (int o = 1; o < 128; o <<= 1) {
    dst[t] = src[t] + ((t >= o) ? src[t - o] : 0);
    __syncthreads();
    int* tmp = src; src = dst; dst = tmp;
  }
  if (t < NBLK_SCAN) bsum[t] = (t == 0) ? 0 : src[t - 1];
}

__global__ __launch_bounds__(256) void scan_c_k(const int* __restrict__ deg,
                                                const int* __restrict__ bsum,
                                                int* __restrict__ rowptr) {
  int t = threadIdx.x;
  int base = blockIdx.x * SCAN_CHUNK;
  int i0 = base + t * 4;
  int v[4];
#pragma unroll
  for (int q = 0; q < 4; ++q) v[q] = (i0 + q < N_NODES) ? deg[i0 + q] : 0;
  int tsum = v[0] + v[1] + v[2] + v[3];
  __shared__ int sa[256], sb[256];
  int* src = sa; int* dst = sb;
  sa[t] = tsum;
  __syncthreads();
  for (int o = 1; o < 256; o <<= 1) {
    dst[t] = src[t] + ((t >= o) ? src[t - o] : 0);
    __syncthreads();
    int* tmp = src; src = dst; dst = tmp;
  }
  int run = bsum[blockIdx.x] + src[t] - tsum;  // exclusive prefix
#pragma unroll
  for (int q = 0; q < 4; ++q) {
    if (i0 + q < N_NODES) rowptr[i0 + q] = run;
    run += v[q];
  }
}

// csr entry: .x = src byte offset into h (src*256), .y = bitcast(dinv[src]*dinv[dst])
__global__ void fill_csr_k(const int* __restrict__ ei, const int* __restrict__ rowptr,
                           const float* __restrict__ dinv,
                           int* __restrict__ cursor, int2* __restrict__ csr) {
  int e = blockIdx.x * blockDim.x + threadIdx.x;
  if (e >= N_EDGES) return;
  int c = ei[N_EDGES + e];
  int r = ei[e];
  int p = atomicAdd(&cursor[c], 1);
  float w = dinv[r] * dinv[c];
  csr[rowptr[c] + p] = make_int2(r << 8, __float_as_int(w));  // r*256
}

// ---------------- GEMM: out[n][c] = sum_k in[n][k]*W[k][c], optional BN+ReLU on input ----------------

template <int K, bool APPLY, bool RELU>
__global__ __launch_bounds__(256) void gemm_k(
    const float* __restrict__ X, const float* __restrict__ W,
    const float* __restrict__ scale, const float* __restrict__ shift,
    float* __restrict__ out, int nrows) {
  constexpr int WROW = K + 4;
  __shared__ float wt[64 * WROW];   // wt[c][k]  (W transposed)
  __shared__ float xs[64 * 68];     // xs[r][k]
  const int tid = threadIdx.x;
  const int tc = tid & 15;
  const int tr = tid >> 4;

  for (int idx = tid; idx < K * 64; idx += 256) {
    int k = idx >> 6, c = idx & 63;
    wt[c * WROW + k] = W[idx];
  }

  const int rowbase = blockIdx.x * 64;
  float acc[4][4] = {};

  for (int kc = 0; kc < K; kc += 64) {
    __syncthreads();
    {
      const int kq = tid & 15;
      const int rr = tid >> 4;
#pragma unroll
      for (int p = 0; p < 4; ++p) {
        int r = rr + p * 16;
        int grow = rowbase + r;
        float4 v = make_float4(0.f, 0.f, 0.f, 0.f);
        if (grow < nrows) v = *(const float4*)(X + (size_t)grow * K + kc + kq * 4);
        if (APPLY) {
          int kg = kc + kq * 4;
          float4 sc = *(const float4*)(scale + kg);
          float4 sh = *(const float4*)(shift + kg);
          v.x = v.x * sc.x + sh.x;
          v.y = v.y * sc.y + sh.y;
          v.z = v.z * sc.z + sh.z;
          v.w = v.w * sc.w + sh.w;
          if (RELU) {
            v.x = fmaxf(v.x, 0.f); v.y = fmaxf(v.y, 0.f);
            v.z = fmaxf(v.z, 0.f); v.w = fmaxf(v.w, 0.f);
          }
        }
        *(float4*)(xs + r * 68 + kq * 4) = v;
      }
    }
    __syncthreads();
#pragma unroll 4
    for (int k0 = 0; k0 < 64; k0 += 4) {
      float4 xv[4], wv[4];
#pragma unroll
      for (int i = 0; i < 4; ++i)
        xv[i] = *(const float4*)(xs + (tr * 4 + i) * 68 + k0);
#pragma unroll
      for (int j = 0; j < 4; ++j)
        wv[j] = *(const float4*)(wt + (tc + 16 * j) * WROW + kc + k0);
#pragma unroll
      for (int i = 0; i < 4; ++i)
#pragma unroll
        for (int j = 0; j < 4; ++j)
          acc[i][j] += xv[i].x * wv[j].x + xv[i].y * wv[j].y +
                       xv[i].z * wv[j].z + xv[i].w * wv[j].w;
    }
  }

#pragma unroll
  for (int i = 0; i < 4; ++i) {
    int grow = rowbase + tr * 4 + i;
    if (grow < nrows) {
#pragma unroll
      for (int j = 0; j < 4; ++j)
        out[(size_t)grow * 64 + tc + 16 * j] = acc[i][j];
    }
  }
}

// ---------------- edge aggregation + fused BN partial stats ----------------
// 16 lanes per node (4 nodes per wave), float4 gathers. Per iteration a wave
// processes 4 edges: one dwordx2 (off,w) pair load (16 lanes same addr ->
// broadcast), one dwordx4 h gather, 4 fmacs.

__global__ __launch_bounds__(256) void agg_k(
    const float* __restrict__ h, const float* __restrict__ dinv,
    const int* __restrict__ rowptr, const int* __restrict__ deg,
    const int2* __restrict__ csr, const float* __restrict__ bias,
    float* __restrict__ out, float* __restrict__ part) {
  const int tid = threadIdx.x;
  const int w = tid >> 6;          // wave in block
  const int lane = tid & 63;
  const int g = lane >> 4;         // node slot within wave (0..3)
  const int q = lane & 15;         // feature quad (features 4q..4q+3)
  const char* hb = (const char*)h;

  float4 bval = *(const float4*)(bias + q * 4);
  float4 s = make_float4(0.f, 0.f, 0.f, 0.f);
  float4 s2 = make_float4(0.f, 0.f, 0.f, 0.f);

  for (int base = blockIdx.x * 16 + w * 4; base < N_NODES; base += AGG_BLOCKS * 16) {
    int n = base + g;
    bool valid = n < N_NODES;
    int nn = valid ? n : 0;
    float dn = dinv[nn];
    int start = rowptr[nn];
    int cnt = valid ? deg[nn] : 0;
    float4 hv = *(const float4*)(hb + ((size_t)nn << 8) + (q << 4));
    float sw = dn * dn;
    float4 acc;
    acc.x = hv.x * sw; acc.y = hv.y * sw; acc.z = hv.z * sw; acc.w = hv.w * sw;
    for (int j = 0; j < cnt; ++j) {
      int2 e = csr[start + j];
      float wt = __int_as_float(e.y);
      float4 v = *(const float4*)(hb + (size_t)(unsigned)e.x + (q << 4));
      acc.x += v.x * wt; acc.y += v.y * wt; acc.z += v.z * wt; acc.w += v.w * wt;
    }
    if (valid) {
      acc.x += bval.x; acc.y += bval.y; acc.z += bval.z; acc.w += bval.w;
      *(float4*)(out + ((size_t)n << 6) + q * 4) = acc;
      s.x += acc.x; s.y += acc.y; s.z += acc.z; s.w += acc.w;
      s2.x += acc.x * acc.x; s2.y += acc.y * acc.y;
      s2.z += acc.z * acc.z; s2.w += acc.w * acc.w;
    }
  }

  // reduce BN partials: 16 rows (w*4+g) x 64 features
  __shared__ float rs[16][64];
  __shared__ float rs2[16][64];
  *(float4*)(&rs[w * 4 + g][q * 4]) = s;
  *(float4*)(&rs2[w * 4 + g][q * 4]) = s2;
  __syncthreads();
  int c = tid & 63;
  int r0 = tid >> 6;  // 0..3
  float a = rs[r0][c] + rs[r0 + 4][c] + rs[r0 + 8][c] + rs[r0 + 12][c];
  float a2 = rs2[r0][c] + rs2[r0 + 4][c] + rs2[r0 + 8][c] + rs2[r0 + 12][c];
  __syncthreads();
  rs[r0][c] = a;
  rs2[r0][c] = a2;
  __syncthreads();
  if (r0 == 0) {
    part[blockIdx.x * 128 + c] = rs[0][c] + rs[1][c] + rs[2][c] + rs[3][c];
    part[blockIdx.x * 128 + 64 + c] = rs2[0][c] + rs2[1][c] + rs2[2][c] + rs2[3][c];
  }
}

__global__ void bnfinal_k(const float* __restrict__ part,
                          const float* __restrict__ gamma, const float* __restrict__ beta,
                          float* __restrict__ scale, float* __restrict__ shift) {
  __shared__ float ls[4][64], ls2[4][64];
  int c = threadIdx.x & 63, q = threadIdx.x >> 6;
  float s = 0.f, s2 = 0.f;
  for (int b = q; b < AGG_BLOCKS; b += 4) {
    s += part[b * 128 + c];
    s2 += part[b * 128 + 64 + c];
  }
  ls[q][c] = s; ls2[q][c] = s2;
  __syncthreads();
  if (q == 0) {
    s = ls[0][c] + ls[1][c] + ls[2][c] + ls[3][c];
    s2 = ls2[0][c] + ls2[1][c] + ls2[2][c] + ls2[3][c];
    float mean = s / (float)N_NODES;
    float var = s2 / (float)N_NODES - mean * mean;
    float sc = gamma[c] * rsqrtf(var + BN_EPS);
    scale[c] = sc;
    shift[c] = beta[c] - mean * sc;
  }
}

// ---------------- pooling (batch is sorted) ----------------

#define POOL_CHUNK 64
__global__ __launch_bounds__(64) void pool_k(
    const float* __restrict__ h, const float* __restrict__ scale,
    const float* __restrict__ shift, const int* __restrict__ batch,
    float* __restrict__ psum, float* __restrict__ pcnt) {
  int lane = threadIdx.x;
  int start = blockIdx.x * POOL_CHUNK;
  if (start >= N_NODES) return;
  int end = min(start + POOL_CHUNK, N_NODES);
  float sc = scale[lane], sh = shift[lane];
  float acc = 0.f, cnt = 0.f;
  int cur = batch[start];
  for (int n = start; n < end; ++n) {
    int g = batch[n];
    if (g != cur) {
      atomicAdd(&psum[cur * 64 + lane], acc);
      if (lane == 0) atomicAdd(&pcnt[cur], cnt);
      acc = 0.f; cnt = 0.f; cur = g;
    }
    acc += h[(size_t)n * 64 + lane] * sc + sh;
    cnt += 1.f;
  }
  atomicAdd(&psum[cur * 64 + lane], acc);
  if (lane == 0) atomicAdd(&pcnt[cur], cnt);
}

// ---------------- centroid classifier ----------------

__global__ void classify_k(const float* __restrict__ psum, const float* __restrict__ pcnt,
                           const float* __restrict__ cg, const float* __restrict__ cm,
                           const float* __restrict__ temp, float* __restrict__ out) {
  int g = blockIdx.x;
  int t = threadIdx.x;
  __shared__ float emb[64];
  __shared__ float dist[208];
  if (t < 64) emb[t] = psum[g * 64 + t] / fmaxf(pcnt[g], 1.0f);
  __syncthreads();
  if (t < 197) {
    const float* C = (t < 5) ? (cg + t * 64) : (cm + (t - 5) * 64);
    float d = 0.f;
#pragma unroll 8
    for (int k = 0; k < 64; ++k) {
      float df = emb[k] - C[k];
      d += df * df;
    }
    dist[t] = d;
  }
  __syncthreads();
  float tv = temp[0];
  if (t == 64) {
    float m = dist[0];
    for (int j = 1; j < 5; ++j) m = fminf(m, dist[j]);
    out[g * 65] = -m / tv;
  }
  if (t < 64) {
    float m = fminf(dist[5 + t * 3], fminf(dist[5 + t * 3 + 1], dist[5 + t * 3 + 2]));
    out[g * 65 + 1 + t] = -m / tv;
  }
}

// ---------------- launch ----------------

extern "C" void kernel_launch(void* const* d_in, const int* in_sizes, int n_in,
                              void* d_out, int out_size, void* d_ws, size_t ws_size,
                              hipStream_t stream) {
  const float* x   = (const float*)d_in[0];
  const int* ei    = (const int*)d_in[1];
  const int* batch = (const int*)d_in[2];
  const float* W1 = (const float*)d_in[3];  const float* b1 = (const float*)d_in[4];
  const float* g1 = (const float*)d_in[5];  const float* be1 = (const float*)d_in[6];
  const float* W2 = (const float*)d_in[7];  const float* b2 = (const float*)d_in[8];
  const float* g2 = (const float*)d_in[9];  const float* be2 = (const float*)d_in[10];
  const float* W3 = (const float*)d_in[11]; const float* b3 = (const float*)d_in[12];
  const float* g3 = (const float*)d_in[13]; const float* be3 = (const float*)d_in[14];
  const float* cg = (const float*)d_in[15];
  const float* cm = (const float*)d_in[16];
  const float* temp = (const float*)d_in[17];
  float* out = (float*)d_out;

  char* ws = (char*)d_ws;
  size_t off = 0;
  auto alloc = [&](size_t bytes) -> void* {
    void* p = ws + off;
    off = (off + bytes + 255) & ~(size_t)255;
    return p;
  };
  int* deg     = (int*)alloc((size_t)N_NODES * 4);
  float* dinv  = (float*)alloc((size_t)N_NODES * 4);
  int* rowptr  = (int*)alloc((size_t)N_NODES * 4);
  int* cursor  = (int*)alloc((size_t)N_NODES * 4);
  int* bsum    = (int*)alloc(1024);
  int2* csr    = (int2*)alloc((size_t)N_EDGES * 8);
  float* hA    = (float*)alloc((size_t)N_NODES * 64 * 4);
  float* hB    = (float*)alloc((size_t)N_NODES * 64 * 4);
  float* part  = (float*)alloc((size_t)AGG_BLOCKS * 128 * 4);
  float* scale = (float*)alloc(64 * 4);
  float* shift = (float*)alloc(64 * 4);
  float* psum  = (float*)alloc(64 * 64 * 4);
  float* pcnt  = (float*)alloc(64 * 4);

  hipMemsetAsync(deg, 0, (size_t)N_NODES * 4, stream);
  hipMemsetAsync(cursor, 0, (size_t)N_NODES * 4, stream);
  hipMemsetAsync(psum, 0, 64 * 64 * 4, stream);
  hipMemsetAsync(pcnt, 0, 64 * 4, stream);

  const int NB_NODE = (N_NODES + 255) / 256;   // 391
  const int NB_EDGE = N_EDGES / 256;           // 12500
  const int NB_GEMM = (N_NODES + 63) / 64;     // 1563
  const int NB_POOL = (N_NODES + POOL_CHUNK - 1) / POOL_CHUNK;

  count_deg_k<<<NB_EDGE, 256, 0, stream>>>(ei, deg);
  dinv_k<<<NB_NODE, 256, 0, stream>>>(deg, dinv);
  scan_a_k<<<NBLK_SCAN, 256, 0, stream>>>(deg, bsum);
  scan_b_k<<<1, 128, 0, stream>>>(bsum);
  scan_c_k<<<NBLK_SCAN, 256, 0, stream>>>(deg, bsum, rowptr);
  fill_csr_k<<<NB_EDGE, 256, 0, stream>>>(ei, rowptr, dinv, cursor, csr);

  // layer 1
  gemm_k<IN_DIM, false, false><<<NB_GEMM, 256, 0, stream>>>(x, W1, nullptr, nullptr, hA, N_NODES);
  agg_k<<<AGG_BLOCKS, 256, 0, stream>>>(hA, dinv, rowptr, deg, csr, b1, hB, part);
  bnfinal_k<<<1, 256, 0, stream>>>(part, g1, be1, scale, shift);

  // layer 2 (BN1+ReLU applied on GEMM input load)
  gemm_k<HID, true, true><<<NB_GEMM, 256, 0, stream>>>(hB, W2, scale, shift, hA, N_NODES);
  agg_k<<<AGG_BLOCKS, 256, 0, stream>>>(hA, dinv, rowptr, deg, csr, b2, hB, part);
  bnfinal_k<<<1, 256, 0, stream>>>(part, g2, be2, scale, shift);

  // layer 3
  gemm_k<HID, true, true><<<NB_GEMM, 256, 0, stream>>>(hB, W3, scale, shift, hA, N_NODES);
  agg_k<<<AGG_BLOCKS, 256, 0, stream>>>(hA, dinv, rowptr, deg, csr, b3, hB, part);
  bnfinal_k<<<1, 256, 0, stream>>>(part, g3, be3, scale, shift);

  // pool (BN3 applied here) + classify
  pool_k<<<NB_POOL, 64, 0, stream>>>(hB, scale, shift, batch, psum, pcnt);
  classify_k<<<N_GRAPHS, 256, 0, stream>>>(psum, pcnt, cg, cm, temp, out);
}

// Round 4
// 970.084 us; speedup vs baseline: 1.7196x; 1.3404x over previous
//
#include <hip/hip_runtime.h>
#include <math.h>

#define N_NODES 100000
#define N_EDGES 3200000
#define N_GRAPHS 64
#define IN_DIM 128
#define HID 64
#define BN_EPS 1e-5f

#define SCAN_CHUNK 1024
#define NBLK_SCAN ((N_NODES + SCAN_CHUNK - 1) / SCAN_CHUNK)  // 98
#define AGG_BLOCKS 2048

typedef unsigned short ushort_t;

__device__ __forceinline__ float bflo(unsigned u) { return __uint_as_float(u << 16); }
__device__ __forceinline__ float bfhi(unsigned u) { return __uint_as_float(u & 0xFFFF0000u); }
__device__ __forceinline__ unsigned f2bf(float f) {  // RNE
  unsigned u = __float_as_uint(f);
  return (u + 0x7FFFu + ((u >> 16) & 1u)) >> 16;
}

// ---------------- degree / CSR build ----------------

__global__ void count_deg_k(const int* __restrict__ ei, int* __restrict__ deg) {
  int e = blockIdx.x * blockDim.x + threadIdx.x;
  if (e < N_EDGES) atomicAdd(&deg[ei[N_EDGES + e]], 1);
}

__global__ void dinv_k(const int* __restrict__ deg, float* __restrict__ dinv) {
  int n = blockIdx.x * blockDim.x + threadIdx.x;
  if (n < N_NODES) dinv[n] = rsqrtf((float)(deg[n] + 1));  // +1 self loop
}

__global__ __launch_bounds__(256) void scan_a_k(const int* __restrict__ deg,
                                                int* __restrict__ bsum) {
  int t = threadIdx.x;
  int base = blockIdx.x * SCAN_CHUNK;
  int s = 0;
  for (int p = 0; p < 4; ++p) {
    int i = base + t + p * 256;
    if (i < N_NODES) s += deg[i];
  }
  __shared__ int red[256];
  red[t] = s; __syncthreads();
  for (int o = 128; o > 0; o >>= 1) {
    if (t < o) red[t] += red[t + o];
    __syncthreads();
  }
  if (t == 0) bsum[blockIdx.x] = red[0];
}

__global__ void scan_b_k(int* bsum) {
  __shared__ int sa[128], sb[128];
  int t = threadIdx.x;
  int* src = sa; int* dst = sb;
  sa[t] = (t < NBLK_SCAN) ? bsum[t] : 0;
  __syncthreads();
  for (int o = 1; o < 128; o <<= 1) {
    dst[t] = src[t] + ((t >= o) ? src[t - o] : 0);
    __syncthreads();
    int* tmp = src; src = dst; dst = tmp;
  }
  if (t < NBLK_SCAN) bsum[t] = (t == 0) ? 0 : src[t - 1];
}

__global__ __launch_bounds__(256) void scan_c_k(const int* __restrict__ deg,
                                                const int* __restrict__ bsum,
                                                int* __restrict__ rowptr) {
  int t = threadIdx.x;
  int base = blockIdx.x * SCAN_CHUNK;
  int i0 = base + t * 4;
  int v[4];
#pragma unroll
  for (int q = 0; q < 4; ++q) v[q] = (i0 + q < N_NODES) ? deg[i0 + q] : 0;
  int tsum = v[0] + v[1] + v[2] + v[3];
  __shared__ int sa[256], sb[256];
  int* src = sa; int* dst = sb;
  sa[t] = tsum;
  __syncthreads();
  for (int o = 1; o < 256; o <<= 1) {
    dst[t] = src[t] + ((t >= o) ? src[t - o] : 0);
    __syncthreads();
    int* tmp = src; src = dst; dst = tmp;
  }
  int run = bsum[blockIdx.x] + src[t] - tsum;  // exclusive prefix
#pragma unroll
  for (int q = 0; q < 4; ++q) {
    if (i0 + q < N_NODES) rowptr[i0 + q] = run;
    run += v[q];
  }
}

// csr entry: .x = src byte offset into bf16 h (src*128), .y = bitcast(dinv[src]*dinv[dst])
__global__ void fill_csr_k(const int* __restrict__ ei, const int* __restrict__ rowptr,
                           const float* __restrict__ dinv,
                           int* __restrict__ cursor, int2* __restrict__ csr) {
  int e = blockIdx.x * blockDim.x + threadIdx.x;
  if (e >= N_EDGES) return;
  int c = ei[N_EDGES + e];
  int r = ei[e];
  int p = atomicAdd(&cursor[c], 1);
  float w = dinv[r] * dinv[c];
  csr[rowptr[c] + p] = make_int2(r << 7, __float_as_int(w));  // r*128 bytes
}

// ---------------- GEMM: out[n][c] = sum_k in[n][k]*W[k][c] -> bf16 out ----------------
// Thread (tc=tid&15, tr=tid>>4) computes rows 4*tr+i, cols 4*tc+j.
// WROW = K+1: 4*WROW ≡ 4 (mod 32) -> 2-way LDS alias only (free on CDNA4).

template <int K, bool APPLY, bool RELU>
__global__ __launch_bounds__(256) void gemm_k(
    const float* __restrict__ X, const float* __restrict__ W,
    const float* __restrict__ scale, const float* __restrict__ shift,
    ushort_t* __restrict__ out, int nrows) {
  constexpr int WROW = K + 1;
  __shared__ float wt[64 * WROW];   // wt[c][k]  (W transposed)
  __shared__ float xs[64 * 68];     // xs[r][k]
  const int tid = threadIdx.x;
  const int tc = tid & 15;
  const int tr = tid >> 4;

  for (int idx = tid; idx < K * 64; idx += 256) {
    int k = idx >> 6, c = idx & 63;
    wt[c * WROW + k] = W[idx];
  }

  const int rowbase = blockIdx.x * 64;
  float acc[4][4] = {};

  for (int kc = 0; kc < K; kc += 64) {
    __syncthreads();
    {
      const int kq = tid & 15;
      const int rr = tid >> 4;
#pragma unroll
      for (int p = 0; p < 4; ++p) {
        int r = rr + p * 16;
        int grow = rowbase + r;
        float4 v = make_float4(0.f, 0.f, 0.f, 0.f);
        if (grow < nrows) v = *(const float4*)(X + (size_t)grow * K + kc + kq * 4);
        if (APPLY) {
          int kg = kc + kq * 4;
          float4 sc = *(const float4*)(scale + kg);
          float4 sh = *(const float4*)(shift + kg);
          v.x = v.x * sc.x + sh.x;
          v.y = v.y * sc.y + sh.y;
          v.z = v.z * sc.z + sh.z;
          v.w = v.w * sc.w + sh.w;
          if (RELU) {
            v.x = fmaxf(v.x, 0.f); v.y = fmaxf(v.y, 0.f);
            v.z = fmaxf(v.z, 0.f); v.w = fmaxf(v.w, 0.f);
          }
        }
        *(float4*)(xs + r * 68 + kq * 4) = v;
      }
    }
    __syncthreads();
#pragma unroll 4
    for (int k0 = 0; k0 < 64; k0 += 4) {
      float4 xv[4], wv[4];
#pragma unroll
      for (int i = 0; i < 4; ++i)
        xv[i] = *(const float4*)(xs + (tr * 4 + i) * 68 + k0);
#pragma unroll
      for (int j = 0; j < 4; ++j)
        wv[j] = *(const float4*)(wt + (4 * tc + j) * WROW + kc + k0);
#pragma unroll
      for (int i = 0; i < 4; ++i)
#pragma unroll
        for (int j = 0; j < 4; ++j)
          acc[i][j] += xv[i].x * wv[j].x + xv[i].y * wv[j].y +
                       xv[i].z * wv[j].z + xv[i].w * wv[j].w;
    }
  }

  char* ob = (char*)out;
#pragma unroll
  for (int i = 0; i < 4; ++i) {
    int grow = rowbase + tr * 4 + i;
    if (grow < nrows) {
      uint2 o;
      o.x = f2bf(acc[i][0]) | (f2bf(acc[i][1]) << 16);
      o.y = f2bf(acc[i][2]) | (f2bf(acc[i][3]) << 16);
      *(uint2*)(ob + (size_t)grow * 128 + tc * 8) = o;
    }
  }
}

// ---------------- edge aggregation (bf16 gather) + fused BN partial stats ----------------
// 16 lanes per node (4 nodes per wave). Per edge: one dwordx2 csr entry
// (broadcast across the 16-lane group), one dwordx2 bf16 gather (128 B row
// fetched by the group in a single instruction), unpack, 4 fma.

__global__ __launch_bounds__(256) void agg_k(
    const ushort_t* __restrict__ h, const float* __restrict__ dinv,
    const int* __restrict__ rowptr, const int* __restrict__ deg,
    const int2* __restrict__ csr, const float* __restrict__ bias,
    float* __restrict__ out, float* __restrict__ sums) {
  const int tid = threadIdx.x;
  const int w = tid >> 6;          // wave in block
  const int lane = tid & 63;
  const int g = lane >> 4;         // node slot within wave (0..3)
  const int q = lane & 15;         // feature quad (features 4q..4q+3)
  const char* hb = (const char*)h;

  float4 bval = *(const float4*)(bias + q * 4);
  float4 s = make_float4(0.f, 0.f, 0.f, 0.f);
  float4 s2 = make_float4(0.f, 0.f, 0.f, 0.f);

  for (int base = blockIdx.x * 16 + w * 4; base < N_NODES; base += AGG_BLOCKS * 16) {
    int n = base + g;
    bool valid = n < N_NODES;
    int nn = valid ? n : 0;
    float dn = dinv[nn];
    int start = rowptr[nn];
    int cnt = valid ? deg[nn] : 0;
    uint2 u = *(const uint2*)(hb + ((size_t)nn << 7) + (q << 3));
    float sw = dn * dn;
    float4 acc;
    acc.x = bflo(u.x) * sw; acc.y = bfhi(u.x) * sw;
    acc.z = bflo(u.y) * sw; acc.w = bfhi(u.y) * sw;
    for (int j = 0; j < cnt; ++j) {
      int2 e = csr[start + j];
      float wt = __int_as_float(e.y);
      uint2 v = *(const uint2*)(hb + (size_t)(unsigned)e.x + (q << 3));
      acc.x += bflo(v.x) * wt; acc.y += bfhi(v.x) * wt;
      acc.z += bflo(v.y) * wt; acc.w += bfhi(v.y) * wt;
    }
    if (valid) {
      acc.x += bval.x; acc.y += bval.y; acc.z += bval.z; acc.w += bval.w;
      *(float4*)(out + ((size_t)n << 6) + q * 4) = acc;
      s.x += acc.x; s.y += acc.y; s.z += acc.z; s.w += acc.w;
      s2.x += acc.x * acc.x; s2.y += acc.y * acc.y;
      s2.z += acc.z * acc.z; s2.w += acc.w * acc.w;
    }
  }

  // reduce BN partials: 16 rows (w*4+g) x 64 features -> atomics into sums[128]
  __shared__ float rs[16][64];
  __shared__ float rs2[16][64];
  *(float4*)(&rs[w * 4 + g][q * 4]) = s;
  *(float4*)(&rs2[w * 4 + g][q * 4]) = s2;
  __syncthreads();
  int c = tid & 63;
  int r0 = tid >> 6;  // 0..3
  float a = rs[r0][c] + rs[r0 + 4][c] + rs[r0 + 8][c] + rs[r0 + 12][c];
  float a2 = rs2[r0][c] + rs2[r0 + 4][c] + rs2[r0 + 8][c] + rs2[r0 + 12][c];
  __syncthreads();
  rs[r0][c] = a;
  rs2[r0][c] = a2;
  __syncthreads();
  if (r0 == 0) {
    atomicAdd(&sums[c], rs[0][c] + rs[1][c] + rs[2][c] + rs[3][c]);
    atomicAdd(&sums[64 + c], rs2[0][c] + rs2[1][c] + rs2[2][c] + rs2[3][c]);
  }
}

__global__ void bnfinal_k(const float* __restrict__ sums,
                          const float* __restrict__ gamma, const float* __restrict__ beta,
                          float* __restrict__ scale, float* __restrict__ shift) {
  int c = threadIdx.x;  // 64 threads
  float mean = sums[c] / (float)N_NODES;
  float var = sums[64 + c] / (float)N_NODES - mean * mean;
  float sc = gamma[c] * rsqrtf(var + BN_EPS);
  scale[c] = sc;
  shift[c] = beta[c] - mean * sc;
}

// ---------------- pooling (batch is sorted) ----------------

#define POOL_CHUNK 32
__global__ __launch_bounds__(64) void pool_k(
    const float* __restrict__ h, const float* __restrict__ scale,
    const float* __restrict__ shift, const int* __restrict__ batch,
    float* __restrict__ psum, float* __restrict__ pcnt) {
  int lane = threadIdx.x;
  int start = blockIdx.x * POOL_CHUNK;
  if (start >= N_NODES) return;
  int end = min(start + POOL_CHUNK, N_NODES);
  float sc = scale[lane], sh = shift[lane];
  float acc = 0.f, cnt = 0.f;
  int cur = batch[start];
  for (int n = start; n < end; ++n) {
    int g = batch[n];
    if (g != cur) {
      atomicAdd(&psum[cur * 64 + lane], acc);
      if (lane == 0) atomicAdd(&pcnt[cur], cnt);
      acc = 0.f; cnt = 0.f; cur = g;
    }
    acc += h[(size_t)n * 64 + lane] * sc + sh;
    cnt += 1.f;
  }
  atomicAdd(&psum[cur * 64 + lane], acc);
  if (lane == 0) atomicAdd(&pcnt[cur], cnt);
}

// ---------------- centroid classifier ----------------

__global__ void classify_k(const float* __restrict__ psum, const float* __restrict__ pcnt,
                           const float* __restrict__ cg, const float* __restrict__ cm,
                           const float* __restrict__ temp, float* __restrict__ out) {
  int g = blockIdx.x;
  int t = threadIdx.x;
  __shared__ float emb[64];
  __shared__ float dist[208];
  if (t < 64) emb[t] = psum[g * 64 + t] / fmaxf(pcnt[g], 1.0f);
  __syncthreads();
  if (t < 197) {
    const float* C = (t < 5) ? (cg + t * 64) : (cm + (t - 5) * 64);
    float d = 0.f;
#pragma unroll 8
    for (int k = 0; k < 64; ++k) {
      float df = emb[k] - C[k];
      d += df * df;
    }
    dist[t] = d;
  }
  __syncthreads();
  float tv = temp[0];
  if (t == 64) {
    float m = dist[0];
    for (int j = 1; j < 5; ++j) m = fminf(m, dist[j]);
    out[g * 65] = -m / tv;
  }
  if (t < 64) {
    float m = fminf(dist[5 + t * 3], fminf(dist[5 + t * 3 + 1], dist[5 + t * 3 + 2]));
    out[g * 65 + 1 + t] = -m / tv;
  }
}

// ---------------- launch ----------------

extern "C" void kernel_launch(void* const* d_in, const int* in_sizes, int n_in,
                              void* d_out, int out_size, void* d_ws, size_t ws_size,
                              hipStream_t stream) {
  const float* x   = (const float*)d_in[0];
  const int* ei    = (const int*)d_in[1];
  const int* batch = (const int*)d_in[2];
  const float* W1 = (const float*)d_in[3];  const float* b1 = (const float*)d_in[4];
  const float* g1 = (const float*)d_in[5];  const float* be1 = (const float*)d_in[6];
  const float* W2 = (const float*)d_in[7];  const float* b2 = (const float*)d_in[8];
  const float* g2 = (const float*)d_in[9];  const float* be2 = (const float*)d_in[10];
  const float* W3 = (const float*)d_in[11]; const float* b3 = (const float*)d_in[12];
  const float* g3 = (const float*)d_in[13]; const float* be3 = (const float*)d_in[14];
  const float* cg = (const float*)d_in[15];
  const float* cm = (const float*)d_in[16];
  const float* temp = (const float*)d_in[17];
  float* out = (float*)d_out;

  char* ws = (char*)d_ws;
  size_t off = 0;
  auto alloc = [&](size_t bytes) -> void* {
    void* p = ws + off;
    off = (off + bytes + 255) & ~(size_t)255;
    return p;
  };
  int* deg       = (int*)alloc((size_t)N_NODES * 4);
  float* dinv    = (float*)alloc((size_t)N_NODES * 4);
  int* rowptr    = (int*)alloc((size_t)N_NODES * 4);
  int* cursor    = (int*)alloc((size_t)N_NODES * 4);
  int* bsum      = (int*)alloc(1024);
  int2* csr      = (int2*)alloc((size_t)N_EDGES * 8);
  ushort_t* hA   = (ushort_t*)alloc((size_t)N_NODES * 64 * 2);  // bf16
  float* hB      = (float*)alloc((size_t)N_NODES * 64 * 4);
  float* sumsAll = (float*)alloc(3 * 128 * 4);
  float* scale   = (float*)alloc(64 * 4);
  float* shift   = (float*)alloc(64 * 4);
  float* psum    = (float*)alloc(64 * 64 * 4);
  float* pcnt    = (float*)alloc(64 * 4);

  hipMemsetAsync(deg, 0, (size_t)N_NODES * 4, stream);
  hipMemsetAsync(cursor, 0, (size_t)N_NODES * 4, stream);
  hipMemsetAsync(sumsAll, 0, 3 * 128 * 4, stream);
  hipMemsetAsync(psum, 0, 64 * 64 * 4, stream);
  hipMemsetAsync(pcnt, 0, 64 * 4, stream);

  const int NB_NODE = (N_NODES + 255) / 256;   // 391
  const int NB_EDGE = N_EDGES / 256;           // 12500
  const int NB_GEMM = (N_NODES + 63) / 64;     // 1563
  const int NB_POOL = (N_NODES + POOL_CHUNK - 1) / POOL_CHUNK;

  count_deg_k<<<NB_EDGE, 256, 0, stream>>>(ei, deg);
  dinv_k<<<NB_NODE, 256, 0, stream>>>(deg, dinv);
  scan_a_k<<<NBLK_SCAN, 256, 0, stream>>>(deg, bsum);
  scan_b_k<<<1, 128, 0, stream>>>(bsum);
  scan_c_k<<<NBLK_SCAN, 256, 0, stream>>>(deg, bsum, rowptr);
  fill_csr_k<<<NB_EDGE, 256, 0, stream>>>(ei, rowptr, dinv, cursor, csr);

  // layer 1
  gemm_k<IN_DIM, false, false><<<NB_GEMM, 256, 0, stream>>>(x, W1, nullptr, nullptr, hA, N_NODES);
  agg_k<<<AGG_BLOCKS, 256, 0, stream>>>(hA, dinv, rowptr, deg, csr, b1, hB, sumsAll);
  bnfinal_k<<<1, 64, 0, stream>>>(sumsAll, g1, be1, scale, shift);

  // layer 2 (BN1+ReLU applied on GEMM input load)
  gemm_k<HID, true, true><<<NB_GEMM, 256, 0, stream>>>(hB, W2, scale, shift, hA, N_NODES);
  agg_k<<<AGG_BLOCKS, 256, 0, stream>>>(hA, dinv, rowptr, deg, csr, b2, hB, sumsAll + 128);
  bnfinal_k<<<1, 64, 0, stream>>>(sumsAll + 128, g2, be2, scale, shift);

  // layer 3
  gemm_k<HID, true, true><<<NB_GEMM, 256, 0, stream>>>(hB, W3, scale, shift, hA, N_NODES);
  agg_k<<<AGG_BLOCKS, 256, 0, stream>>>(hA, dinv, rowptr, deg, csr, b3, hB, sumsAll + 256);
  bnfinal_k<<<1, 64, 0, stream>>>(sumsAll + 256, g3, be3, scale, shift);

  // pool (BN3 applied here) + classify
  pool_k<<<NB_POOL, 64, 0, stream>>>(hB, scale, shift, batch, psum, pcnt);
  classify_k<<<N_GRAPHS, 256, 0, stream>>>(psum, pcnt, cg, cm, temp, out);
}

// Round 5
// 643.670 us; speedup vs baseline: 2.5917x; 1.5071x over previous
//
#include <hip/hip_runtime.h>
#include <math.h>

#define N_NODES 100000
#define N_EDGES 3200000
#define N_GRAPHS 64
#define IN_DIM 128
#define HID 64
#define BN_EPS 1e-5f

#define PSHIFT 9
#define PBS 512
#define NPB ((N_NODES + PBS - 1) / PBS)  // 196
#define PART_BLOCKS 256
#define CHUNK_E (N_EDGES / PART_BLOCKS)  // 12500
#define AGG_BLOCKS 2048

typedef unsigned short ushort_t;

__device__ __forceinline__ float bflo(unsigned u) { return __uint_as_float(u << 16); }
__device__ __forceinline__ float bfhi(unsigned u) { return __uint_as_float(u & 0xFFFF0000u); }
__device__ __forceinline__ unsigned f2bf(float f) {  // RNE
  unsigned u = __float_as_uint(f);
  return (u + 0x7FFFu + ((u >> 16) & 1u)) >> 16;
}

// ---------------- CSR build: two-level bucket sort ----------------
// Level 1: 196 coarse buckets (dst>>9). Level 2: per-bucket (512 nodes)
// histogram+scan+place in an L2-resident window. No unclustered global
// scatter anywhere: partition writes ~256 B contiguous runs of packed 4 B
// entries; place scatters inside a 131 KB window.

__global__ __launch_bounds__(256) void ghist_k(const int* __restrict__ ei,
                                               int* __restrict__ gh) {
  __shared__ int h[NPB];
  for (int i = threadIdx.x; i < NPB; i += 256) h[i] = 0;
  __syncthreads();
  int stride = gridDim.x * 256;
  for (int e = blockIdx.x * 256 + threadIdx.x; e < N_EDGES; e += stride)
    atomicAdd(&h[ei[N_EDGES + e] >> PSHIFT], 1);
  __syncthreads();
  for (int i = threadIdx.x; i < NPB; i += 256) {
    int v = h[i];
    if (v) atomicAdd(&gh[i], v);
  }
}

__global__ __launch_bounds__(256) void gscan_k(const int* __restrict__ gh,
                                               int* __restrict__ boff,
                                               int* __restrict__ gcur) {
  __shared__ int sa[256], sb[256];
  int t = threadIdx.x;
  int v = (t < NPB) ? gh[t] : 0;
  sa[t] = v;
  __syncthreads();
  int* src = sa; int* dst = sb;
  for (int o = 1; o < 256; o <<= 1) {
    dst[t] = src[t] + ((t >= o) ? src[t - o] : 0);
    __syncthreads();
    int* tmp = src; src = dst; dst = tmp;
  }
  if (t < NPB) {
    int excl = src[t] - v;
    boff[t] = excl;
    gcur[t] = excl;
    if (t == NPB - 1) boff[NPB] = src[t];
  }
}

// partition: per-block LDS hist -> one global atomic per (block,bucket) ->
// scatter packed entries into private contiguous runs.
__global__ __launch_bounds__(512) void part_k(const int* __restrict__ ei,
                                              int* __restrict__ gcur,
                                              unsigned* __restrict__ tmp) {
  __shared__ int lh[NPB];
  __shared__ int lcur[NPB];
  int t = threadIdx.x;
  for (int i = t; i < NPB; i += 512) lh[i] = 0;
  __syncthreads();
  int c0 = blockIdx.x * CHUNK_E;
  int c1 = c0 + CHUNK_E;
  for (int e = c0 + t; e < c1; e += 512)
    atomicAdd(&lh[ei[N_EDGES + e] >> PSHIFT], 1);
  __syncthreads();
  for (int i = t; i < NPB; i += 512) {
    int v = lh[i];
    lcur[i] = v ? atomicAdd(&gcur[i], v) : 0;
  }
  __syncthreads();
  for (int e = c0 + t; e < c1; e += 512) {
    int dst = ei[N_EDGES + e];
    int src = ei[e];
    int b = dst >> PSHIFT;
    int p = atomicAdd(&lcur[b], 1);
    tmp[p] = ((unsigned)(dst & (PBS - 1)) << 17) | (unsigned)src;
  }
}

// per-bucket histogram + scan -> deg, dinv, rowptr
__global__ __launch_bounds__(512) void bhist_k(
    const unsigned* __restrict__ tmp, const int* __restrict__ boff,
    int* __restrict__ deg, float* __restrict__ dinv, int* __restrict__ rowptr) {
  int b = blockIdx.x;
  int base = boff[b], end = boff[b + 1];
  int t = threadIdx.x;
  __shared__ int cnt[PBS];
  __shared__ int sa[PBS], sb[PBS];
  cnt[t] = 0;
  __syncthreads();
  for (int i = base + t; i < end; i += 512)
    atomicAdd(&cnt[tmp[i] >> 17], 1);
  __syncthreads();
  int v = cnt[t];
  sa[t] = v;
  __syncthreads();
  int* src = sa; int* dst = sb;
  for (int o = 1; o < PBS; o <<= 1) {
    dst[t] = src[t] + ((t >= o) ? src[t - o] : 0);
    __syncthreads();
    int* tmp2 = src; src = dst; dst = tmp2;
  }
  int n = b * PBS + t;
  if (n < N_NODES) {
    deg[n] = v;
    dinv[n] = rsqrtf((float)(v + 1));  // +1 self loop
    rowptr[n] = base + src[t] - v;     // exclusive
  }
}

// per-bucket place with pre-multiplied weight (dinv complete by now)
__global__ __launch_bounds__(512) void bplace_k(
    const unsigned* __restrict__ tmp, const int* __restrict__ boff,
    const int* __restrict__ rowptr, const float* __restrict__ dinv,
    int2* __restrict__ csr) {
  int b = blockIdx.x;
  int base = boff[b], end = boff[b + 1];
  int t = threadIdx.x;
  __shared__ int cur[PBS];
  __shared__ float ld[PBS];
  int n = b * PBS + t;
  if (n < N_NODES) {
    cur[t] = rowptr[n] - base;
    ld[t] = dinv[n];
  } else {
    cur[t] = 0; ld[t] = 0.f;
  }
  __syncthreads();
  for (int i = base + t; i < end; i += 512) {
    unsigned u = tmp[i];
    int d = u >> 17;
    int src = u & 0x1FFFFu;
    int p = atomicAdd(&cur[d], 1);
    float w = ld[d] * dinv[src];
    csr[base + p] = make_int2(src << 7, __float_as_int(w));  // src*128 bytes
  }
}

// ---------------- GEMM: out[n][c] = sum_k in[n][k]*W[k][c] -> bf16 out ----------------

template <int K, bool APPLY, bool RELU>
__global__ __launch_bounds__(256) void gemm_k(
    const float* __restrict__ X, const float* __restrict__ W,
    const float* __restrict__ scale, const float* __restrict__ shift,
    ushort_t* __restrict__ out, int nrows) {
  constexpr int WROW = K + 1;
  __shared__ float wt[64 * WROW];   // wt[c][k]  (W transposed)
  __shared__ float xs[64 * 68];     // xs[r][k]
  const int tid = threadIdx.x;
  const int tc = tid & 15;
  const int tr = tid >> 4;

  for (int idx = tid; idx < K * 64; idx += 256) {
    int k = idx >> 6, c = idx & 63;
    wt[c * WROW + k] = W[idx];
  }

  const int rowbase = blockIdx.x * 64;
  float acc[4][4] = {};

  for (int kc = 0; kc < K; kc += 64) {
    __syncthreads();
    {
      const int kq = tid & 15;
      const int rr = tid >> 4;
#pragma unroll
      for (int p = 0; p < 4; ++p) {
        int r = rr + p * 16;
        int grow = rowbase + r;
        float4 v = make_float4(0.f, 0.f, 0.f, 0.f);
        if (grow < nrows) v = *(const float4*)(X + (size_t)grow * K + kc + kq * 4);
        if (APPLY) {
          int kg = kc + kq * 4;
          float4 sc = *(const float4*)(scale + kg);
          float4 sh = *(const float4*)(shift + kg);
          v.x = v.x * sc.x + sh.x;
          v.y = v.y * sc.y + sh.y;
          v.z = v.z * sc.z + sh.z;
          v.w = v.w * sc.w + sh.w;
          if (RELU) {
            v.x = fmaxf(v.x, 0.f); v.y = fmaxf(v.y, 0.f);
            v.z = fmaxf(v.z, 0.f); v.w = fmaxf(v.w, 0.f);
          }
        }
        *(float4*)(xs + r * 68 + kq * 4) = v;
      }
    }
    __syncthreads();
#pragma unroll 4
    for (int k0 = 0; k0 < 64; k0 += 4) {
      float4 xv[4], wv[4];
#pragma unroll
      for (int i = 0; i < 4; ++i)
        xv[i] = *(const float4*)(xs + (tr * 4 + i) * 68 + k0);
#pragma unroll
      for (int j = 0; j < 4; ++j)
        wv[j] = *(const float4*)(wt + (4 * tc + j) * WROW + kc + k0);
#pragma unroll
      for (int i = 0; i < 4; ++i)
#pragma unroll
        for (int j = 0; j < 4; ++j)
          acc[i][j] += xv[i].x * wv[j].x + xv[i].y * wv[j].y +
                       xv[i].z * wv[j].z + xv[i].w * wv[j].w;
    }
  }

  char* ob = (char*)out;
#pragma unroll
  for (int i = 0; i < 4; ++i) {
    int grow = rowbase + tr * 4 + i;
    if (grow < nrows) {
      uint2 o;
      o.x = f2bf(acc[i][0]) | (f2bf(acc[i][1]) << 16);
      o.y = f2bf(acc[i][2]) | (f2bf(acc[i][3]) << 16);
      *(uint2*)(ob + (size_t)grow * 128 + tc * 8) = o;
    }
  }
}

// ---------------- edge aggregation (bf16 gather, x4 unroll) + fused BN stats ----------------

__global__ __launch_bounds__(256) void agg_k(
    const ushort_t* __restrict__ h, const float* __restrict__ dinv,
    const int* __restrict__ rowptr, const int* __restrict__ deg,
    const int2* __restrict__ csr, const float* __restrict__ bias,
    float* __restrict__ out, float* __restrict__ sums) {
  const int tid = threadIdx.x;
  const int w = tid >> 6;          // wave in block
  const int lane = tid & 63;
  const int g = lane >> 4;         // node slot within wave (0..3)
  const int q = lane & 15;         // feature quad (features 4q..4q+3)
  const char* hb = (const char*)h;

  float4 bval = *(const float4*)(bias + q * 4);
  float4 s = make_float4(0.f, 0.f, 0.f, 0.f);
  float4 s2 = make_float4(0.f, 0.f, 0.f, 0.f);

  for (int base = blockIdx.x * 16 + w * 4; base < N_NODES; base += AGG_BLOCKS * 16) {
    int n = base + g;
    bool valid = n < N_NODES;
    int nn = valid ? n : 0;
    float dn = dinv[nn];
    int start = rowptr[nn];
    int cnt = valid ? deg[nn] : 0;
    uint2 u = *(const uint2*)(hb + ((size_t)nn << 7) + (q << 3));
    float sw = dn * dn;
    float4 acc;
    acc.x = bflo(u.x) * sw; acc.y = bfhi(u.x) * sw;
    acc.z = bflo(u.y) * sw; acc.w = bfhi(u.y) * sw;
    int j = 0;
    for (; j + 4 <= cnt; j += 4) {  // 4 independent gathers in flight
      int2 e0 = csr[start + j];
      int2 e1 = csr[start + j + 1];
      int2 e2 = csr[start + j + 2];
      int2 e3 = csr[start + j + 3];
      uint2 v0 = *(const uint2*)(hb + (size_t)(unsigned)e0.x + (q << 3));
      uint2 v1 = *(const uint2*)(hb + (size_t)(unsigned)e1.x + (q << 3));
      uint2 v2 = *(const uint2*)(hb + (size_t)(unsigned)e2.x + (q << 3));
      uint2 v3 = *(const uint2*)(hb + (size_t)(unsigned)e3.x + (q << 3));
      float w0 = __int_as_float(e0.y), w1 = __int_as_float(e1.y);
      float w2 = __int_as_float(e2.y), w3 = __int_as_float(e3.y);
      acc.x += bflo(v0.x) * w0; acc.y += bfhi(v0.x) * w0;
      acc.z += bflo(v0.y) * w0; acc.w += bfhi(v0.y) * w0;
      acc.x += bflo(v1.x) * w1; acc.y += bfhi(v1.x) * w1;
      acc.z += bflo(v1.y) * w1; acc.w += bfhi(v1.y) * w1;
      acc.x += bflo(v2.x) * w2; acc.y += bfhi(v2.x) * w2;
      acc.z += bflo(v2.y) * w2; acc.w += bfhi(v2.y) * w2;
      acc.x += bflo(v3.x) * w3; acc.y += bfhi(v3.x) * w3;
      acc.z += bflo(v3.y) * w3; acc.w += bfhi(v3.y) * w3;
    }
    for (; j < cnt; ++j) {
      int2 e = csr[start + j];
      float wt = __int_as_float(e.y);
      uint2 v = *(const uint2*)(hb + (size_t)(unsigned)e.x + (q << 3));
      acc.x += bflo(v.x) * wt; acc.y += bfhi(v.x) * wt;
      acc.z += bflo(v.y) * wt; acc.w += bfhi(v.y) * wt;
    }
    if (valid) {
      acc.x += bval.x; acc.y += bval.y; acc.z += bval.z; acc.w += bval.w;
      *(float4*)(out + ((size_t)n << 6) + q * 4) = acc;
      s.x += acc.x; s.y += acc.y; s.z += acc.z; s.w += acc.w;
      s2.x += acc.x * acc.x; s2.y += acc.y * acc.y;
      s2.z += acc.z * acc.z; s2.w += acc.w * acc.w;
    }
  }

  __shared__ float rs[16][64];
  __shared__ float rs2[16][64];
  *(float4*)(&rs[w * 4 + g][q * 4]) = s;
  *(float4*)(&rs2[w * 4 + g][q * 4]) = s2;
  __syncthreads();
  int c = tid & 63;
  int r0 = tid >> 6;  // 0..3
  float a = rs[r0][c] + rs[r0 + 4][c] + rs[r0 + 8][c] + rs[r0 + 12][c];
  float a2 = rs2[r0][c] + rs2[r0 + 4][c] + rs2[r0 + 8][c] + rs2[r0 + 12][c];
  __syncthreads();
  rs[r0][c] = a;
  rs2[r0][c] = a2;
  __syncthreads();
  if (r0 == 0) {
    atomicAdd(&sums[c], rs[0][c] + rs[1][c] + rs[2][c] + rs[3][c]);
    atomicAdd(&sums[64 + c], rs2[0][c] + rs2[1][c] + rs2[2][c] + rs2[3][c]);
  }
}

__global__ void bnfinal_k(const float* __restrict__ sums,
                          const float* __restrict__ gamma, const float* __restrict__ beta,
                          float* __restrict__ scale, float* __restrict__ shift) {
  int c = threadIdx.x;  // 64 threads
  float mean = sums[c] / (float)N_NODES;
  float var = sums[64 + c] / (float)N_NODES - mean * mean;
  float sc = gamma[c] * rsqrtf(var + BN_EPS);
  scale[c] = sc;
  shift[c] = beta[c] - mean * sc;
}

// ---------------- pooling (batch is sorted) ----------------

#define POOL_CHUNK 32
__global__ __launch_bounds__(64) void pool_k(
    const float* __restrict__ h, const float* __restrict__ scale,
    const float* __restrict__ shift, const int* __restrict__ batch,
    float* __restrict__ psum, float* __restrict__ pcnt) {
  int lane = threadIdx.x;
  int start = blockIdx.x * POOL_CHUNK;
  if (start >= N_NODES) return;
  int end = min(start + POOL_CHUNK, N_NODES);
  float sc = scale[lane], sh = shift[lane];
  float acc = 0.f, cnt = 0.f;
  int cur = batch[start];
  for (int n = start; n < end; ++n) {
    int g = batch[n];
    if (g != cur) {
      atomicAdd(&psum[cur * 64 + lane], acc);
      if (lane == 0) atomicAdd(&pcnt[cur], cnt);
      acc = 0.f; cnt = 0.f; cur = g;
    }
    acc += h[(size_t)n * 64 + lane] * sc + sh;
    cnt += 1.f;
  }
  atomicAdd(&psum[cur * 64 + lane], acc);
  if (lane == 0) atomicAdd(&pcnt[cur], cnt);
}

// ---------------- centroid classifier ----------------

__global__ void classify_k(const float* __restrict__ psum, const float* __restrict__ pcnt,
                           const float* __restrict__ cg, const float* __restrict__ cm,
                           const float* __restrict__ temp, float* __restrict__ out) {
  int g = blockIdx.x;
  int t = threadIdx.x;
  __shared__ float emb[64];
  __shared__ float dist[208];
  if (t < 64) emb[t] = psum[g * 64 + t] / fmaxf(pcnt[g], 1.0f);
  __syncthreads();
  if (t < 197) {
    const float* C = (t < 5) ? (cg + t * 64) : (cm + (t - 5) * 64);
    float d = 0.f;
#pragma unroll 8
    for (int k = 0; k < 64; ++k) {
      float df = emb[k] - C[k];
      d += df * df;
    }
    dist[t] = d;
  }
  __syncthreads();
  float tv = temp[0];
  if (t == 64) {
    float m = dist[0];
    for (int j = 1; j < 5; ++j) m = fminf(m, dist[j]);
    out[g * 65] = -m / tv;
  }
  if (t < 64) {
    float m = fminf(dist[5 + t * 3], fminf(dist[5 + t * 3 + 1], dist[5 + t * 3 + 2]));
    out[g * 65 + 1 + t] = -m / tv;
  }
}

// ---------------- launch ----------------

extern "C" void kernel_launch(void* const* d_in, const int* in_sizes, int n_in,
                              void* d_out, int out_size, void* d_ws, size_t ws_size,
                              hipStream_t stream) {
  const float* x   = (const float*)d_in[0];
  const int* ei    = (const int*)d_in[1];
  const int* batch = (const int*)d_in[2];
  const float* W1 = (const float*)d_in[3];  const float* b1 = (const float*)d_in[4];
  const float* g1 = (const float*)d_in[5];  const float* be1 = (const float*)d_in[6];
  const float* W2 = (const float*)d_in[7];  const float* b2 = (const float*)d_in[8];
  const float* g2 = (const float*)d_in[9];  const float* be2 = (const float*)d_in[10];
  const float* W3 = (const float*)d_in[11]; const float* b3 = (const float*)d_in[12];
  const float* g3 = (const float*)d_in[13]; const float* be3 = (const float*)d_in[14];
  const float* cg = (const float*)d_in[15];
  const float* cm = (const float*)d_in[16];
  const float* temp = (const float*)d_in[17];
  float* out = (float*)d_out;

  char* ws = (char*)d_ws;
  size_t off = 0;
  auto alloc = [&](size_t bytes) -> void* {
    void* p = ws + off;
    off = (off + bytes + 255) & ~(size_t)255;
    return p;
  };
  int* gh        = (int*)alloc((size_t)NPB * 4);
  int* boff      = (int*)alloc((size_t)(NPB + 1) * 4);
  int* gcur      = (int*)alloc((size_t)NPB * 4);
  unsigned* tmp  = (unsigned*)alloc((size_t)N_EDGES * 4);
  int2* csr      = (int2*)alloc((size_t)N_EDGES * 8);
  int* deg       = (int*)alloc((size_t)N_NODES * 4);
  float* dinv    = (float*)alloc((size_t)N_NODES * 4);
  int* rowptr    = (int*)alloc((size_t)N_NODES * 4);
  ushort_t* hA   = (ushort_t*)alloc((size_t)N_NODES * 64 * 2);  // bf16
  float* hB      = (float*)alloc((size_t)N_NODES * 64 * 4);
  float* sumsAll = (float*)alloc(3 * 128 * 4);
  float* scale   = (float*)alloc(64 * 4);
  float* shift   = (float*)alloc(64 * 4);
  float* psum    = (float*)alloc(64 * 64 * 4);
  float* pcnt    = (float*)alloc(64 * 4);

  hipMemsetAsync(gh, 0, (size_t)NPB * 4, stream);
  hipMemsetAsync(sumsAll, 0, 3 * 128 * 4, stream);
  hipMemsetAsync(psum, 0, 64 * 64 * 4, stream);
  hipMemsetAsync(pcnt, 0, 64 * 4, stream);

  const int NB_GEMM = (N_NODES + 63) / 64;   // 1563
  const int NB_POOL = (N_NODES + POOL_CHUNK - 1) / POOL_CHUNK;

  // CSR build (two-level bucket sort, no unclustered scatter)
  ghist_k<<<512, 256, 0, stream>>>(ei, gh);
  gscan_k<<<1, 256, 0, stream>>>(gh, boff, gcur);
  part_k<<<PART_BLOCKS, 512, 0, stream>>>(ei, gcur, tmp);
  bhist_k<<<NPB, 512, 0, stream>>>(tmp, boff, deg, dinv, rowptr);
  bplace_k<<<NPB, 512, 0, stream>>>(tmp, boff, rowptr, dinv, csr);

  // layer 1
  gemm_k<IN_DIM, false, false><<<NB_GEMM, 256, 0, stream>>>(x, W1, nullptr, nullptr, hA, N_NODES);
  agg_k<<<AGG_BLOCKS, 256, 0, stream>>>(hA, dinv, rowptr, deg, csr, b1, hB, sumsAll);
  bnfinal_k<<<1, 64, 0, stream>>>(sumsAll, g1, be1, scale, shift);

  // layer 2 (BN1+ReLU applied on GEMM input load)
  gemm_k<HID, true, true><<<NB_GEMM, 256, 0, stream>>>(hB, W2, scale, shift, hA, N_NODES);
  agg_k<<<AGG_BLOCKS, 256, 0, stream>>>(hA, dinv, rowptr, deg, csr, b2, hB, sumsAll + 128);
  bnfinal_k<<<1, 64, 0, stream>>>(sumsAll + 128, g2, be2, scale, shift);

  // layer 3
  gemm_k<HID, true, true><<<NB_GEMM, 256, 0, stream>>>(hB, W3, scale, shift, hA, N_NODES);
  agg_k<<<AGG_BLOCKS, 256, 0, stream>>>(hA, dinv, rowptr, deg, csr, b3, hB, sumsAll + 256);
  bnfinal_k<<<1, 64, 0, stream>>>(sumsAll + 256, g3, be3, scale, shift);

  // pool (BN3 applied here) + classify
  pool_k<<<NB_POOL, 64, 0, stream>>>(hB, scale, shift, batch, psum, pcnt);
  classify_k<<<N_GRAPHS, 256, 0, stream>>>(psum, pcnt, cg, cm, temp, out);
}